// Round 10
// baseline (106.601 us; speedup 1.0000x reference)
//
#include <hip/hip_runtime.h>

typedef unsigned short u16;
typedef __attribute__((ext_vector_type(8))) __bf16 bf16x8;
typedef __attribute__((ext_vector_type(8))) unsigned short u16x8;
typedef __attribute__((ext_vector_type(4))) float f32x4;

__device__ __forceinline__ u16 f2bf(float f) {
  unsigned u = __builtin_bit_cast(unsigned, f);
  unsigned r = u + 0x7fffu + ((u >> 16) & 1u);
  return (u16)(r >> 16);
}

__device__ __forceinline__ float wave_sum(float v) {
#pragma unroll
  for (int o = 32; o; o >>= 1) v += __shfl_xor(v, o, 64);
  return v;
}

// ===== K1: xin build (0..255) + plane sums (256..1279) + Mt rows (1280..1535) =====
// xin layout: [b][h][cg(16)][pxp(80)][slot(4)][8ch] bf16. pxp=px+1; cols 0,65..79 zero.
// slot s at pxp holds channel-octet g = s ^ ((pxp>>1)&3)  (bank swizzle).
__global__ void k_pre(const float* __restrict__ tgt, const float* __restrict__ prev,
                      const float* __restrict__ src, const float* __restrict__ kw,
                      const float* __restrict__ lw, const float* __restrict__ aw,
                      const float* __restrict__ gamma,
                      u16* __restrict__ xin, float* __restrict__ ssum,
                      float* __restrict__ Mt) {
  __shared__ u16 lt[16896];             // 256*66 u16 (aliased by other branches)
  int tid = threadIdx.x;
  if (blockIdx.x >= 1280) {             // ---- Mt row ----
    float* E = (float*)lt;
    int o = blockIdx.x - 1280;
    if (tid < 32) {
      float s = 0.f;
      for (int o2 = 0; o2 < 32; ++o2) s += aw[o * 288 + 256 + o2] * lw[o2 * 64 + tid];
      E[tid] = s;
    }
    __syncthreads();
    float s = 0.f;
    for (int a = 0; a < 32; ++a) s += E[a] * kw[a * 256 + tid];
    Mt[o * 256 + tid] = gamma[0] * (aw[o * 288 + tid] + 4096.f * s) + (o == tid ? 1.f : 0.f);
    return;
  }
  if (blockIdx.x >= 256) {              // ---- plane sum of source_enc ----
    float* red = (float*)lt;
    int plane = blockIdx.x - 256;
    const float* p = src + (size_t)plane * 4096;
    float s = 0.f;
#pragma unroll
    for (int i = 0; i < 4; ++i) {
      f32x4 v = *(const f32x4*)(p + (i * 256 + tid) * 4);
      s += v[0] + v[1] + v[2] + v[3];
    }
    s = wave_sum(s);
    if ((tid & 63) == 0) red[tid >> 6] = s;
    __syncthreads();
    if (tid == 0) ssum[plane] = red[0] + red[1] + red[2] + red[3];
    return;
  }
  // ---- xin build (coalesced loads -> LDS transpose -> swizzled u16x8 stores) ----
  int b = blockIdx.x >> 6, h = blockIdx.x & 63;
  u16* slab = xin + (size_t)(b * 64 + h) * 40960;
  for (int i = tid; i < 8192; i += 256) {
    int cg = i >> 9, rest = i & 511;
    int colidx = rest >> 5, e = rest & 31;
    int pxp = (colidx == 0) ? 0 : (64 + colidx);
    slab[cg * 2560 + pxp * 32 + e] = 0;
  }
  for (int it = 0; it < 16; ++it) {
    int fi = it * 256 + tid;
    int c = fi >> 4, w4 = fi & 15;
    f32x4 v = *(const f32x4*)(tgt + ((size_t)(b * 256 + c) * 64 + h) * 64 + w4 * 4);
    int base = c * 66 + w4 * 4;
    lt[base] = f2bf(v[0]); lt[base + 1] = f2bf(v[1]);
    lt[base + 2] = f2bf(v[2]); lt[base + 3] = f2bf(v[3]);
  }
  __syncthreads();
  for (int it = 0; it < 8; ++it) {      // write cg 0..7
    int i = it * 256 + tid;
    int o = i & 31, w = i >> 5;
    u16x8 v;
#pragma unroll
    for (int k = 0; k < 8; ++k) v[k] = lt[(o * 8 + k) * 66 + w];
    int cg = o >> 2, g = o & 3, pxp = w + 1;
    int slot = g ^ ((pxp >> 1) & 3);
    *(u16x8*)(slab + cg * 2560 + pxp * 32 + slot * 8) = v;
  }
  __syncthreads();
  for (int it = 0; it < 8; ++it) {
    int pi = it * 256 + tid;
    int cc = pi >> 3, wq = pi & 7;
    f32x4 v = *(const f32x4*)(prev + ((size_t)(b * 256 + cc) * 32 + (h >> 1)) * 32 + wq * 4);
    int base = cc * 66 + wq * 8;
    u16 b0 = f2bf(v[0]), b1 = f2bf(v[1]), b2 = f2bf(v[2]), b3 = f2bf(v[3]);
    lt[base] = b0; lt[base + 1] = b0; lt[base + 2] = b1; lt[base + 3] = b1;
    lt[base + 4] = b2; lt[base + 5] = b2; lt[base + 6] = b3; lt[base + 7] = b3;
  }
  __syncthreads();
  for (int it = 0; it < 8; ++it) {      // write cg 8..15
    int i = it * 256 + tid;
    int o = i & 31, w = i >> 5;
    u16x8 v;
#pragma unroll
    for (int k = 0; k < 8; ++k) v[k] = lt[(o * 8 + k) * 66 + w];
    int cg = 8 + (o >> 2), g = o & 3, pxp = w + 1;
    int slot = g ^ ((pxp >> 1) & 3);
    *(u16x8*)(slab + cg * 2560 + pxp * 32 + slot * 8) = v;
  }
}

// ===== K3: folded conv weights w3 + cd2; dvec inline =====
// w3 u16 idx = (tap*16+cg)*4096 + kbq*1024 + oc*8 + j, channel cf = cg*32+kbq*8+j
__global__ void k_w3(const float* __restrict__ cw, const float* __restrict__ Mt,
                     const float* __restrict__ ssum,
                     const float* __restrict__ qw, const float* __restrict__ qb,
                     const float* __restrict__ kb, const float* __restrict__ lw,
                     const float* __restrict__ lb, const float* __restrict__ aw,
                     const float* __restrict__ ab, const float* __restrict__ gamma,
                     u16* __restrict__ w3, float* __restrict__ cd2) {
  __shared__ float qs_l[128], amap_l[128], dvec_l[1024];
  __shared__ float cwl[4096];
  __shared__ float part[512];
  int tid = threadIdx.x;                // 512 threads
  if (tid < 128) {
    int bb = tid >> 5, o = tid & 31;
    float s = 4096.f * qb[o];
    for (int c = 0; c < 256; ++c) s += qw[o * 256 + c] * ssum[bb * 256 + c];
    qs_l[tid] = s;
  }
  __syncthreads();
  if (tid < 128) {
    int bb = tid >> 5, o2 = tid & 31;
    float s = 0.f, kt = 0.f;
    for (int o = 0; o < 32; ++o) {
      s += lw[o2 * 64 + 32 + o] * qs_l[bb * 32 + o];
      kt += lw[o2 * 64 + o] * kb[o];
    }
    amap_l[tid] = 4096.f * (kt + lb[o2]) + s;
  }
  __syncthreads();
  float g = gamma[0];
  for (int i = tid; i < 1024; i += 512) {
    int bb = i >> 8, c = i & 255;
    float s = ab[c];
    for (int o2 = 0; o2 < 32; ++o2) s += aw[c * 288 + 256 + o2] * amap_l[bb * 32 + o2];
    dvec_l[i] = g * s;
  }
  int blk = blockIdx.x;                 // 144 = 9*16
  int tap = blk >> 4, ocg = blk & 15;
  for (int e = tid; e < 4096; e += 512) {
    int oc = e >> 9, c = e & 511;
    cwl[e] = cw[(size_t)((ocg * 8 + oc) * 512 + c) * 9 + tap];
  }
  __syncthreads();
  int wv = tid >> 6, l = tid & 63;
  int c2 = l * 4;
  f32x4 acc = {0.f, 0.f, 0.f, 0.f};
  for (int c = 0; c < 256; ++c) {
    float wc = cwl[wv * 512 + c];
    f32x4 m = *(const f32x4*)(Mt + c * 256 + c2);
#pragma unroll
    for (int j = 0; j < 4; ++j) acc[j] += wc * m[j];
  }
  int ocf = ocg * 8 + wv;
#pragma unroll
  for (int j2 = 0; j2 < 4; ++j2) {
    int cf = c2 + j2;
    w3[(tap * 16 + (cf >> 5)) * 4096 + ((cf >> 3) & 3) * 1024 + ocf * 8 + (cf & 7)] = f2bf(acc[j2]);
    cf = 256 + c2 + j2;
    w3[(tap * 16 + (cf >> 5)) * 4096 + ((cf >> 3) & 3) * 1024 + ocf * 8 + (cf & 7)] =
        f2bf(cwl[wv * 512 + (c2 + j2 + 256)]);
  }
  {
    int bb = tid >> 7, oc = (tid >> 4) & 7, cp = tid & 15;
    float s = 0.f;
#pragma unroll
    for (int i = 0; i < 16; ++i) s += cwl[oc * 512 + cp * 16 + i] * dvec_l[bb * 256 + cp * 16 + i];
    part[tid] = s;
  }
  __syncthreads();
  if (tid < 32) {
    int bb = tid >> 3, oc = tid & 7;
    float s = 0.f;
#pragma unroll
    for (int cp = 0; cp < 16; ++cp) s += part[bb * 128 + oc * 16 + cp];
    cd2[(size_t)(bb * 128 + ocg * 8 + oc) * 9 + tap] = s;
  }
}

// ===== K4: conv. A-fragments (w3) register-prefetched from L2; only xin in LDS. =====
// block=(b,h): M=128 oc, N=64 px. 4 waves = 2 wr x 2 wpx, wave tile M64 x N32.
// 16 cg x 3 dy steps; per step per wave 24 MFMA. ONE barrier per cg (16 total).
// A: 12 bf16x8 per step, double-buffered A0/A1 (static idx), prefetched 1 step ahead.
// xin: reg-staged (T14) global->reg at cg top, ds_write->other buf before barrier.
__global__ __launch_bounds__(256) void k_conv(const u16* __restrict__ xin,
                                              const u16* __restrict__ w3,
                                              const float* __restrict__ cd2,
                                              float* __restrict__ out) {
  __shared__ u16 lds[15360];            // 2 bufs x 3 rows x 2560 u16 = 30 KB
  int bid = blockIdx.x;                 // 256
  int lid = (bid & 7) * 32 + (bid >> 3);  // XCD-chunked
  int b = lid >> 6, h = lid & 63;
  int tid = threadIdx.x, l = tid & 63, wv = tid >> 6;
  int wr = wv & 1, wpx = wv >> 1;
  int r = l & 15, kb4 = l >> 4;

  // pre-zero OOR rows in BOTH bufs once (stage skips them forever after)
  if (h == 0 || h == 63) {
    int row = (h == 0) ? 0 : 2;
    u16x8 zz;
#pragma unroll
    for (int q = 0; q < 8; ++q) zz[q] = 0;
    for (int i = tid; i < 320; i += 256)
      if (i < 320) {
        *(u16x8*)(lds + row * 2560 + i * 8) = zz;
        *(u16x8*)(lds + 7680 + row * 2560 + i * 8) = zz;
      }
  }

  u16x8 st[4];
  auto XLOAD = [&](int cg, bool skip) {  // global -> regs (issue early)
    if (skip) return;
#pragma unroll
    for (int q = 0; q < 4; ++q) {
      int c = q * 256 + tid;
      if (c < 960) {
        int row = c / 320, part = c - row * 320;
        int grow = h - 1 + row;
        if ((unsigned)grow < 64u)
          st[q] = *(const u16x8*)(xin + ((size_t)(b * 64 + grow) * 16 + cg) * 2560 + part * 8);
      }
    }
  };
  auto XWRITE = [&](int buf, bool skip) {  // regs -> LDS (just before barrier)
    if (skip) return;
#pragma unroll
    for (int q = 0; q < 4; ++q) {
      int c = q * 256 + tid;
      if (c < 960) {
        int row = c / 320, part = c - row * 320;
        int grow = h - 1 + row;
        if ((unsigned)grow < 64u)
          *(u16x8*)(lds + buf * 7680 + row * 2560 + part * 8) = st[q];
      }
    }
  };

  auto ALOAD = [&](bf16x8 (&A)[12], int cg, int dy, bool skip) {
    if (skip) return;
#pragma unroll
    for (int dx = 0; dx < 3; ++dx) {
      const u16* base = w3 + (((dy * 3 + dx) * 16 + cg) << 12) + kb4 * 1024 + wr * 512 + r * 8;
#pragma unroll
      for (int mf = 0; mf < 4; ++mf)
        A[dx * 4 + mf] = *(const bf16x8*)(base + mf * 128);
    }
  };

  f32x4 acc[4][2];
#pragma unroll
  for (int mf = 0; mf < 4; ++mf)
#pragma unroll
    for (int nf = 0; nf < 2; ++nf) acc[mf][nf] = f32x4{0.f, 0.f, 0.f, 0.f};

  bf16x8 A0[12], A1[12];

  auto DOSTEP = [&](bf16x8 (&Ac)[12], bf16x8 (&An)[12], int buf, int dy,
                    int cgN, int dyN, bool skipPf) {
    ALOAD(An, cgN, dyN, skipPf);        // prefetch next step's A (L2, ~1 step cover)
    const u16* xrow = lds + buf * 7680 + dy * 2560;
#pragma unroll
    for (int dx = 0; dx < 3; ++dx) {
      bf16x8 bv[2];
#pragma unroll
      for (int nf = 0; nf < 2; ++nf) {
        int pxp = wpx * 32 + nf * 16 + r + dx;
        int slot = kb4 ^ ((pxp >> 1) & 3);
        bv[nf] = *(const bf16x8*)(xrow + pxp * 32 + slot * 8);
      }
#pragma unroll
      for (int mf = 0; mf < 4; ++mf)
#pragma unroll
        for (int nf = 0; nf < 2; ++nf)
          acc[mf][nf] = __builtin_amdgcn_mfma_f32_16x16x32_bf16(Ac[dx * 4 + mf], bv[nf],
                                                                acc[mf][nf], 0, 0, 0);
    }
  };

  // prologue: stage cg0 -> buf0, preload A0 = (cg0, dy0)
  XLOAD(0, false);
  ALOAD(A0, 0, 0, false);
  XWRITE(0, false);
  __syncthreads();

  for (int cp = 0; cp < 8; ++cp) {
    int c0 = 2 * cp, c1 = 2 * cp + 1;
    bool last = (cp == 7);
    // ---- cg c0 (buf 0) ----
    XLOAD(c1, false);
    DOSTEP(A0, A1, 0, 0, c0, 1, false);
    DOSTEP(A1, A0, 0, 1, c0, 2, false);
    DOSTEP(A0, A1, 0, 2, c1, 0, false);
    XWRITE(1, false);
    __syncthreads();
    // ---- cg c1 (buf 1) ----
    XLOAD(c1 + 1, last);
    DOSTEP(A1, A0, 1, 0, c1, 1, false);
    DOSTEP(A0, A1, 1, 1, c1, 2, false);
    DOSTEP(A1, A0, 1, 2, c1 + 1, 0, last);
    XWRITE(0, last);
    if (!last) __syncthreads();
  }

  // ---- epilogue: border-masked constant correction + plain stores ----
  bool dy0v = (h > 0), dy2v = (h < 63);
#pragma unroll
  for (int mf = 0; mf < 4; ++mf) {
#pragma unroll
    for (int j = 0; j < 4; ++j) {
      int oc = wr * 64 + mf * 16 + kb4 * 4 + j;
      const float* cd = cd2 + (size_t)(b * 128 + oc) * 9;
      float sAll = 0.f, sL = 0.f, sR = 0.f;
#pragma unroll
      for (int dy3 = 0; dy3 < 3; ++dy3) {
        bool v = (dy3 == 1) || (dy3 == 0 ? dy0v : dy2v);
        if (v) {
          sAll += cd[dy3 * 3] + cd[dy3 * 3 + 1] + cd[dy3 * 3 + 2];
          sL += cd[dy3 * 3];
          sR += cd[dy3 * 3 + 2];
        }
      }
#pragma unroll
      for (int nf = 0; nf < 2; ++nf) {
        int px = wpx * 32 + nf * 16 + r;
        float corr = sAll - (px == 0 ? sL : 0.f) - (px == 63 ? sR : 0.f);
        out[(size_t)(b * 128 + oc) * 4096 + h * 64 + px] = acc[mf][nf][j] + corr;
      }
    }
  }
}

// ===== K5: in-place instance norm + relu =====
__global__ void k_norm(float* __restrict__ out) {
  int plane = blockIdx.x;               // 512 = 4*128
  float* p = out + (size_t)plane * 4096;
  int t = threadIdx.x;
  f32x4 v[4];
  float s = 0.f, s2 = 0.f;
#pragma unroll
  for (int i = 0; i < 4; ++i) {
    v[i] = *(const f32x4*)(p + (i * 256 + t) * 4);
#pragma unroll
    for (int k = 0; k < 4; ++k) { s += v[i][k]; s2 += v[i][k] * v[i][k]; }
  }
  s = wave_sum(s); s2 = wave_sum(s2);
  __shared__ float rs[4], rs2[4];
  if ((t & 63) == 0) { rs[t >> 6] = s; rs2[t >> 6] = s2; }
  __syncthreads();
  float S = rs[0] + rs[1] + rs[2] + rs[3];
  float S2 = rs2[0] + rs2[1] + rs2[2] + rs2[3];
  float mean = S * (1.f / 4096.f);
  float var = S2 * (1.f / 4096.f) - mean * mean;
  float inv = rsqrtf(var + 1e-5f);
#pragma unroll
  for (int i = 0; i < 4; ++i) {
    f32x4 o;
#pragma unroll
    for (int k = 0; k < 4; ++k) {
      float y = (v[i][k] - mean) * inv;
      o[k] = y > 0.f ? y : 0.f;
    }
    *(f32x4*)(p + (i * 256 + t) * 4) = o;
  }
}

extern "C" void kernel_launch(void* const* d_in, const int* in_sizes, int n_in,
                              void* d_out, int out_size, void* d_ws, size_t ws_size,
                              hipStream_t stream) {
  const float* src    = (const float*)d_in[0];
  const float* tgt    = (const float*)d_in[1];
  const float* prev   = (const float*)d_in[2];
  const float* key_w  = (const float*)d_in[3];
  const float* key_b  = (const float*)d_in[4];
  const float* qry_w  = (const float*)d_in[5];
  const float* qry_b  = (const float*)d_in[6];
  const float* lin_w  = (const float*)d_in[7];
  const float* lin_b  = (const float*)d_in[8];
  const float* attn_w = (const float*)d_in[9];
  const float* attn_b = (const float*)d_in[10];
  const float* gamma  = (const float*)d_in[11];
  const float* conv_w = (const float*)d_in[12];
  // d_in[13] = conv_b: dropped — per-(b,oc) constant cancels under instance norm.

  char* ws = (char*)d_ws;
  size_t off = 0;
  u16*   xin  = (u16*)(ws + off);  off += 20971520;            // 256 slabs * 40960 u16
  float* ssum = (float*)(ws + off); off += 4096;               // 4*256
  float* Mt   = (float*)(ws + off); off += 262144;             // 256*256
  float* cd2  = (float*)(ws + off); off += 18432;              // 4*128*9
  u16*   w3   = (u16*)(ws + off);  off += 1179648;             // 9*16*4096 u16
  float* out  = (float*)d_out;

  k_pre<<<1536, 256, 0, stream>>>(tgt, prev, src, key_w, lin_w, attn_w, gamma,
                                  xin, ssum, Mt);
  k_w3<<<144, 512, 0, stream>>>(conv_w, Mt, ssum, qry_w, qry_b, key_b, lin_w, lin_b,
                                attn_w, attn_b, gamma, w3, cd2);
  k_conv<<<256, 256, 0, stream>>>(xin, w3, cd2, out);
  k_norm<<<512, 256, 0, stream>>>(out);
}

// Round 11
// 74.625 us; speedup vs baseline: 1.4285x; 1.4285x over previous
//
#include <hip/hip_runtime.h>

typedef unsigned short u16;
typedef __attribute__((ext_vector_type(8))) __bf16 bf16x8;
typedef __attribute__((ext_vector_type(8))) unsigned short u16x8;
typedef __attribute__((ext_vector_type(4))) float f32x4;

__device__ __forceinline__ u16 f2bf(float f) {
  unsigned u = __builtin_bit_cast(unsigned, f);
  unsigned r = u + 0x7fffu + ((u >> 16) & 1u);
  return (u16)(r >> 16);
}

__device__ __forceinline__ float wave_sum(float v) {
#pragma unroll
  for (int o = 32; o; o >>= 1) v += __shfl_xor(v, o, 64);
  return v;
}

// async global(16B/lane) -> LDS (wave-uniform dest; per-lane global src)
__device__ __forceinline__ void gl2lds16(const u16* g, u16* l) {
  __builtin_amdgcn_global_load_lds(
      (const __attribute__((address_space(1))) unsigned int*)(const void*)g,
      (__attribute__((address_space(3))) unsigned int*)(void*)l, 16, 0, 0);
}

// ===== K1: xin build (0..255) + plane sums (256..1279) + Mt rows (1280..1535) =====
// xin layout: [b][h][cg(16)][pxp(80)][slot(4)][8ch] bf16. pxp=px+1; cols 0,65..79 zero.
// slot s at pxp holds channel-octet g = s ^ ((pxp>>1)&3)  (bank swizzle).
__global__ void k_pre(const float* __restrict__ tgt, const float* __restrict__ prev,
                      const float* __restrict__ src, const float* __restrict__ kw,
                      const float* __restrict__ lw, const float* __restrict__ aw,
                      const float* __restrict__ gamma,
                      u16* __restrict__ xin, float* __restrict__ ssum,
                      float* __restrict__ Mt) {
  __shared__ u16 lt[16896];             // 256*66 u16 (aliased by other branches)
  int tid = threadIdx.x;
  if (blockIdx.x >= 1280) {             // ---- Mt row ----
    float* E = (float*)lt;
    int o = blockIdx.x - 1280;
    if (tid < 32) {
      float s = 0.f;
      for (int o2 = 0; o2 < 32; ++o2) s += aw[o * 288 + 256 + o2] * lw[o2 * 64 + tid];
      E[tid] = s;
    }
    __syncthreads();
    float s = 0.f;
    for (int a = 0; a < 32; ++a) s += E[a] * kw[a * 256 + tid];
    Mt[o * 256 + tid] = gamma[0] * (aw[o * 288 + tid] + 4096.f * s) + (o == tid ? 1.f : 0.f);
    return;
  }
  if (blockIdx.x >= 256) {              // ---- plane sum of source_enc ----
    float* red = (float*)lt;
    int plane = blockIdx.x - 256;
    const float* p = src + (size_t)plane * 4096;
    float s = 0.f;
#pragma unroll
    for (int i = 0; i < 4; ++i) {
      f32x4 v = *(const f32x4*)(p + (i * 256 + tid) * 4);
      s += v[0] + v[1] + v[2] + v[3];
    }
    s = wave_sum(s);
    if ((tid & 63) == 0) red[tid >> 6] = s;
    __syncthreads();
    if (tid == 0) ssum[plane] = red[0] + red[1] + red[2] + red[3];
    return;
  }
  // ---- xin build (coalesced loads -> LDS transpose -> swizzled u16x8 stores) ----
  int b = blockIdx.x >> 6, h = blockIdx.x & 63;
  u16* slab = xin + (size_t)(b * 64 + h) * 40960;
  for (int i = tid; i < 8192; i += 256) {
    int cg = i >> 9, rest = i & 511;
    int colidx = rest >> 5, e = rest & 31;
    int pxp = (colidx == 0) ? 0 : (64 + colidx);
    slab[cg * 2560 + pxp * 32 + e] = 0;
  }
  for (int it = 0; it < 16; ++it) {
    int fi = it * 256 + tid;
    int c = fi >> 4, w4 = fi & 15;
    f32x4 v = *(const f32x4*)(tgt + ((size_t)(b * 256 + c) * 64 + h) * 64 + w4 * 4);
    int base = c * 66 + w4 * 4;
    lt[base] = f2bf(v[0]); lt[base + 1] = f2bf(v[1]);
    lt[base + 2] = f2bf(v[2]); lt[base + 3] = f2bf(v[3]);
  }
  __syncthreads();
  for (int it = 0; it < 8; ++it) {      // write cg 0..7
    int i = it * 256 + tid;
    int o = i & 31, w = i >> 5;
    u16x8 v;
#pragma unroll
    for (int k = 0; k < 8; ++k) v[k] = lt[(o * 8 + k) * 66 + w];
    int cg = o >> 2, g = o & 3, pxp = w + 1;
    int slot = g ^ ((pxp >> 1) & 3);
    *(u16x8*)(slab + cg * 2560 + pxp * 32 + slot * 8) = v;
  }
  __syncthreads();
  for (int it = 0; it < 8; ++it) {
    int pi = it * 256 + tid;
    int cc = pi >> 3, wq = pi & 7;
    f32x4 v = *(const f32x4*)(prev + ((size_t)(b * 256 + cc) * 32 + (h >> 1)) * 32 + wq * 4);
    int base = cc * 66 + wq * 8;
    u16 b0 = f2bf(v[0]), b1 = f2bf(v[1]), b2 = f2bf(v[2]), b3 = f2bf(v[3]);
    lt[base] = b0; lt[base + 1] = b0; lt[base + 2] = b1; lt[base + 3] = b1;
    lt[base + 4] = b2; lt[base + 5] = b2; lt[base + 6] = b3; lt[base + 7] = b3;
  }
  __syncthreads();
  for (int it = 0; it < 8; ++it) {      // write cg 8..15
    int i = it * 256 + tid;
    int o = i & 31, w = i >> 5;
    u16x8 v;
#pragma unroll
    for (int k = 0; k < 8; ++k) v[k] = lt[(o * 8 + k) * 66 + w];
    int cg = 8 + (o >> 2), g = o & 3, pxp = w + 1;
    int slot = g ^ ((pxp >> 1) & 3);
    *(u16x8*)(slab + cg * 2560 + pxp * 32 + slot * 8) = v;
  }
}

// ===== K3: folded conv weights w3 + cd2; dvec inline =====
// w3 u16 idx = (tap*16+cg)*4096 + kbq*1024 + oc*8 + j, channel cf = cg*32+kbq*8+j
__global__ void k_w3(const float* __restrict__ cw, const float* __restrict__ Mt,
                     const float* __restrict__ ssum,
                     const float* __restrict__ qw, const float* __restrict__ qb,
                     const float* __restrict__ kb, const float* __restrict__ lw,
                     const float* __restrict__ lb, const float* __restrict__ aw,
                     const float* __restrict__ ab, const float* __restrict__ gamma,
                     u16* __restrict__ w3, float* __restrict__ cd2) {
  __shared__ float qs_l[128], amap_l[128], dvec_l[1024];
  __shared__ float cwl[4096];
  __shared__ float part[512];
  int tid = threadIdx.x;                // 512 threads
  if (tid < 128) {
    int bb = tid >> 5, o = tid & 31;
    float s = 4096.f * qb[o];
    for (int c = 0; c < 256; ++c) s += qw[o * 256 + c] * ssum[bb * 256 + c];
    qs_l[tid] = s;
  }
  __syncthreads();
  if (tid < 128) {
    int bb = tid >> 5, o2 = tid & 31;
    float s = 0.f, kt = 0.f;
    for (int o = 0; o < 32; ++o) {
      s += lw[o2 * 64 + 32 + o] * qs_l[bb * 32 + o];
      kt += lw[o2 * 64 + o] * kb[o];
    }
    amap_l[tid] = 4096.f * (kt + lb[o2]) + s;
  }
  __syncthreads();
  float g = gamma[0];
  for (int i = tid; i < 1024; i += 512) {
    int bb = i >> 8, c = i & 255;
    float s = ab[c];
    for (int o2 = 0; o2 < 32; ++o2) s += aw[c * 288 + 256 + o2] * amap_l[bb * 32 + o2];
    dvec_l[i] = g * s;
  }
  int blk = blockIdx.x;                 // 144 = 9*16
  int tap = blk >> 4, ocg = blk & 15;
  for (int e = tid; e < 4096; e += 512) {
    int oc = e >> 9, c = e & 511;
    cwl[e] = cw[(size_t)((ocg * 8 + oc) * 512 + c) * 9 + tap];
  }
  __syncthreads();
  int wv = tid >> 6, l = tid & 63;
  int c2 = l * 4;
  f32x4 acc = {0.f, 0.f, 0.f, 0.f};
  for (int c = 0; c < 256; ++c) {
    float wc = cwl[wv * 512 + c];
    f32x4 m = *(const f32x4*)(Mt + c * 256 + c2);
#pragma unroll
    for (int j = 0; j < 4; ++j) acc[j] += wc * m[j];
  }
  int ocf = ocg * 8 + wv;
#pragma unroll
  for (int j2 = 0; j2 < 4; ++j2) {
    int cf = c2 + j2;
    w3[(tap * 16 + (cf >> 5)) * 4096 + ((cf >> 3) & 3) * 1024 + ocf * 8 + (cf & 7)] = f2bf(acc[j2]);
    cf = 256 + c2 + j2;
    w3[(tap * 16 + (cf >> 5)) * 4096 + ((cf >> 3) & 3) * 1024 + ocf * 8 + (cf & 7)] =
        f2bf(cwl[wv * 512 + (c2 + j2 + 256)]);
  }
  {
    int bb = tid >> 7, oc = (tid >> 4) & 7, cp = tid & 15;
    float s = 0.f;
#pragma unroll
    for (int i = 0; i < 16; ++i) s += cwl[oc * 512 + cp * 16 + i] * dvec_l[bb * 256 + cp * 16 + i];
    part[tid] = s;
  }
  __syncthreads();
  if (tid < 32) {
    int bb = tid >> 3, oc = tid & 7;
    float s = 0.f;
#pragma unroll
    for (int cp = 0; cp < 16; ++cp) s += part[bb * 128 + oc * 16 + cp];
    cd2[(size_t)(bb * 128 + ocg * 8 + oc) * 9 + tap] = s;
  }
}

// ===== K4: conv, counted-vmcnt pipeline, 8 WAVES. block=(b,h): M=128 oc, N=64 px. =====
// K = 16 cg x 3 dy steps (48); each step = 3 dx taps.
// 8 waves = 4 wr (M32) x 2 wpx (N32); per wave per step: 12 MFMA, 12 ds_read_b128.
// w3: 3 bufs, issued 2 steps ahead (3 loads/wave/step). xin: 2 bufs, issued at dy0
// (2 loads/wave). Waits: vmcnt(3) at dy0 (leave w3(t+1)), vmcnt(5) else
// (leave w3(t+1)+xin) — never 0 in the loop. Dummy loads keep counts uniform.
__global__ __launch_bounds__(512) void k_conv(const u16* __restrict__ xin,
                                              const u16* __restrict__ w3,
                                              const float* __restrict__ cd2,
                                              float* __restrict__ out) {
  __shared__ u16 lds[52736];            // w3 3x12288 | xin 2x7680 | dummy 512
  const int XIN0 = 36864, DUMMY = 52224;
  int bid = blockIdx.x;                 // 256
  int lid = (bid & 7) * 32 + (bid >> 3);  // XCD-chunked
  int b = lid >> 6, h = lid & 63;
  int tid = threadIdx.x, l = tid & 63, wv = tid >> 6;   // wv 0..7
  int wr = wv & 3, wpx = wv >> 2;       // wave: M32 quarter x N32 half
  int r = l & 15, kb4 = l >> 4;

  // pre-zero OOR xin rows in both bufs (their stage chunks are dummy-redirected)
  if (h == 0 || h == 63) {
    int row = (h == 0) ? 0 : 2;
    for (int i = tid; i < 640; i += 512) {
      int bu = i / 320, off = (i % 320) * 8;
      u16x8 zz;
#pragma unroll
      for (int q = 0; q < 8; ++q) zz[q] = 0;
      *(u16x8*)(lds + XIN0 + bu * 7680 + row * 2560 + off) = zz;
    }
  }

  auto ISSUE_W3 = [&](int c2, int dy2, int buf, bool dummy) {
    u16* dst0 = lds + buf * 12288;
#pragma unroll
    for (int i = 0; i < 3; ++i) {
      int k = wv + 8 * i;               // 0..23
      int dx = k >> 3, part = k & 7;
      const u16* src = dummy ? (w3 + l * 8)
          : (w3 + (size_t)(((dy2 * 3 + dx) * 16 + c2) << 12) + part * 512 + l * 8);
      u16* dst = dummy ? (lds + DUMMY) : (dst0 + dx * 4096 + part * 512);
      gl2lds16(src, dst);
    }
  };
  auto ISSUE_XIN = [&](int c1, int buf, bool dummyAll) {
    u16* dst0 = lds + XIN0 + buf * 7680;
#pragma unroll
    for (int i = 0; i < 2; ++i) {
      int k = wv + 8 * i;               // 0..15 (k==15 is the pad chunk)
      int row = k / 5, part = k - row * 5;
      int grow = h - 1 + row;
      bool dm = dummyAll || (k == 15) || ((unsigned)grow >= 64u);
      const u16* src = dm ? (xin + l * 8)
          : (xin + ((size_t)(b * 64 + grow) * 16 + c1) * 2560 + part * 512 + l * 8);
      u16* dst = dm ? (lds + DUMMY) : (dst0 + row * 2560 + part * 512);
      gl2lds16(src, dst);
    }
  };

  f32x4 acc[2][2];
#pragma unroll
  for (int mf = 0; mf < 2; ++mf)
#pragma unroll
    for (int nf = 0; nf < 2; ++nf) acc[mf][nf] = f32x4{0.f, 0.f, 0.f, 0.f};

  // prologue: W3(step0), XIN(cg0), W3(step1)  -> 8 loads in flight per wave
  ISSUE_W3(0, 0, 0, false);
  ISSUE_XIN(0, 0, false);
  ISSUE_W3(0, 1, 1, false);

  for (int c = 0; c < 16; ++c) {
#pragma unroll
    for (int dy = 0; dy < 3; ++dy) {
      if (dy == 0) asm volatile("s_waitcnt vmcnt(3) lgkmcnt(0)" ::: "memory");
      else         asm volatile("s_waitcnt vmcnt(5) lgkmcnt(0)" ::: "memory");
      __builtin_amdgcn_s_barrier();
      __builtin_amdgcn_sched_barrier(0);
      {
        int c2 = c + ((dy + 2) / 3);
        ISSUE_W3(c2, (dy + 2) % 3, (dy + 2) % 3, c2 > 15);
      }
      if (dy == 0) ISSUE_XIN(c + 1, (c + 1) & 1, c + 1 > 15);
      const u16* wbuf = lds + dy * 12288;           // s%3 == dy
      const u16* xrow = lds + XIN0 + (c & 1) * 7680 + dy * 2560;
#pragma unroll
      for (int dx = 0; dx < 3; ++dx) {
        bf16x8 av[2];
#pragma unroll
        for (int mf = 0; mf < 2; ++mf)
          av[mf] = *(const bf16x8*)(wbuf + dx * 4096 + kb4 * 1024 + (wr * 32 + mf * 16 + r) * 8);
        bf16x8 bv[2];
#pragma unroll
        for (int nf = 0; nf < 2; ++nf) {
          int pxp = wpx * 32 + nf * 16 + r + dx;
          int slot = kb4 ^ ((pxp >> 1) & 3);
          bv[nf] = *(const bf16x8*)(xrow + pxp * 32 + slot * 8);
        }
#pragma unroll
        for (int mf = 0; mf < 2; ++mf)
#pragma unroll
          for (int nf = 0; nf < 2; ++nf)
            acc[mf][nf] = __builtin_amdgcn_mfma_f32_16x16x32_bf16(av[mf], bv[nf], acc[mf][nf], 0, 0, 0);
      }
    }
  }

  // ---- epilogue: border-masked constant correction + plain stores (no atomics) ----
  bool dy0v = (h > 0), dy2v = (h < 63);
#pragma unroll
  for (int mf = 0; mf < 2; ++mf) {
#pragma unroll
    for (int j = 0; j < 4; ++j) {
      int oc = wr * 32 + mf * 16 + kb4 * 4 + j;
      const float* cd = cd2 + (size_t)(b * 128 + oc) * 9;
      float sAll = 0.f, sL = 0.f, sR = 0.f;
#pragma unroll
      for (int dy3 = 0; dy3 < 3; ++dy3) {
        bool v = (dy3 == 1) || (dy3 == 0 ? dy0v : dy2v);
        if (v) {
          sAll += cd[dy3 * 3] + cd[dy3 * 3 + 1] + cd[dy3 * 3 + 2];
          sL += cd[dy3 * 3];
          sR += cd[dy3 * 3 + 2];
        }
      }
#pragma unroll
      for (int nf = 0; nf < 2; ++nf) {
        int px = wpx * 32 + nf * 16 + r;
        float corr = sAll - (px == 0 ? sL : 0.f) - (px == 63 ? sR : 0.f);
        out[(size_t)(b * 128 + oc) * 4096 + h * 64 + px] = acc[mf][nf][j] + corr;
      }
    }
  }
}

// ===== K5: in-place instance norm + relu =====
__global__ void k_norm(float* __restrict__ out) {
  int plane = blockIdx.x;               // 512 = 4*128
  float* p = out + (size_t)plane * 4096;
  int t = threadIdx.x;
  f32x4 v[4];
  float s = 0.f, s2 = 0.f;
#pragma unroll
  for (int i = 0; i < 4; ++i) {
    v[i] = *(const f32x4*)(p + (i * 256 + t) * 4);
#pragma unroll
    for (int k = 0; k < 4; ++k) { s += v[i][k]; s2 += v[i][k] * v[i][k]; }
  }
  s = wave_sum(s); s2 = wave_sum(s2);
  __shared__ float rs[4], rs2[4];
  if ((t & 63) == 0) { rs[t >> 6] = s; rs2[t >> 6] = s2; }
  __syncthreads();
  float S = rs[0] + rs[1] + rs[2] + rs[3];
  float S2 = rs2[0] + rs2[1] + rs2[2] + rs2[3];
  float mean = S * (1.f / 4096.f);
  float var = S2 * (1.f / 4096.f) - mean * mean;
  float inv = rsqrtf(var + 1e-5f);
#pragma unroll
  for (int i = 0; i < 4; ++i) {
    f32x4 o;
#pragma unroll
    for (int k = 0; k < 4; ++k) {
      float y = (v[i][k] - mean) * inv;
      o[k] = y > 0.f ? y : 0.f;
    }
    *(f32x4*)(p + (i * 256 + t) * 4) = o;
  }
}

extern "C" void kernel_launch(void* const* d_in, const int* in_sizes, int n_in,
                              void* d_out, int out_size, void* d_ws, size_t ws_size,
                              hipStream_t stream) {
  const float* src    = (const float*)d_in[0];
  const float* tgt    = (const float*)d_in[1];
  const float* prev   = (const float*)d_in[2];
  const float* key_w  = (const float*)d_in[3];
  const float* key_b  = (const float*)d_in[4];
  const float* qry_w  = (const float*)d_in[5];
  const float* qry_b  = (const float*)d_in[6];
  const float* lin_w  = (const float*)d_in[7];
  const float* lin_b  = (const float*)d_in[8];
  const float* attn_w = (const float*)d_in[9];
  const float* attn_b = (const float*)d_in[10];
  const float* gamma  = (const float*)d_in[11];
  const float* conv_w = (const float*)d_in[12];
  // d_in[13] = conv_b: dropped — per-(b,oc) constant cancels under instance norm.

  char* ws = (char*)d_ws;
  size_t off = 0;
  u16*   xin  = (u16*)(ws + off);  off += 20971520;            // 256 slabs * 40960 u16
  float* ssum = (float*)(ws + off); off += 4096;               // 4*256
  float* Mt   = (float*)(ws + off); off += 262144;             // 256*256
  float* cd2  = (float*)(ws + off); off += 18432;              // 4*128*9
  u16*   w3   = (u16*)(ws + off);  off += 1179648;             // 9*16*4096 u16
  float* out  = (float*)d_out;

  k_pre<<<1536, 256, 0, stream>>>(tgt, prev, src, key_w, lin_w, attn_w, gamma,
                                  xin, ssum, Mt);
  k_w3<<<144, 512, 0, stream>>>(conv_w, Mt, ssum, qry_w, qry_b, key_b, lin_w, lin_b,
                                attn_w, attn_b, gamma, w3, cd2);
  k_conv<<<256, 512, 0, stream>>>(xin, w3, cd2, out);
  k_norm<<<512, 256, 0, stream>>>(out);
}